// Round 15
// baseline (2471.409 us; speedup 1.0000x reference)
//
#include <hip/hip_runtime.h>
#include <cstdint>
#include <cstddef>

// Problem constants
#define N_NEU   4096
#define N_IN    1024
#define B_SZ    8
#define T_STEPS 500
#define NBLK    256                 // 256 sim blocks x 128 posts (32 hslices x 8 b)
#define FF_WORDS (B_SZ * T_STEPS * 16)

// ws layout:
//   [0)       int seq[8][64]        2 KB  (per-batch row; entries 0..31 = hslice seq)
//   [2048)    u64 tmask[64]         512 B (per-64-group exc-type bit masks)
//   [2560)    u64 mb[2][8][64]      8 KB  (dbuf spike masks, 64 words/batch)
//   [10752)   u64 ffmask[B*T*16]    512 KB (input-spike bitmasks)
#define WS_SEQ_OFF   0
#define WS_TM_OFF    2048
#define WS_MB_OFF    2560
#define WS_FFM_OFF   10752

__global__ __launch_bounds__(64) void snn_init(const int* __restrict__ ci,
                                               int* __restrict__ seq,
                                               unsigned long long* __restrict__ tmask,
                                               unsigned long long* __restrict__ mb) {
    const int k = blockIdx.x, l = threadIdx.x;   // 64 blocks x 64 threads
    unsigned long long m = __ballot(ci[(k << 6) + l] == 0);
    if (l == 0) tmask[k] = m;
    const int idx = (k << 6) + l;
    if (idx < 512)  seq[idx] = 0;
    if (idx < 1024) mb[idx] = 0ULL;
}

// input spikes (B,T,NI) -> bitmask words, 64 elems per word, ascending order
__global__ __launch_bounds__(256) void snn_ffmask(const float* __restrict__ inspk,
                                                  unsigned long long* __restrict__ ffmask) {
    int gid = blockIdx.x * 256 + threadIdx.x;
    int wid = gid >> 6, lane = gid & 63;
    int nw  = (gridDim.x * 256) >> 6;
    for (int w = wid; w < FF_WORDS; w += nw) {
        float v = inspk[(size_t)w * 64 + lane];
        unsigned long long m = __ballot(v > 0.5f);
        if (lane == 0) ffmask[w] = m;
    }
}

// Extract set bits of a PRE-FILTERED distributed mask (lane l holds word l,
// bit b -> index l*64+b) into lds as entries (idx<<1)|1, globally ascending,
// padded to a multiple of 64 with 0-entries (idx 0, invalid bit clear).
// Returns real count (wave-uniform). Shuffles are wave-local; lane = tid&63.
__device__ __forceinline__ int extract_f(unsigned long long m, int* lds, int lane) {
    int pc  = __popcll(m);
    int sum = pc;
#pragma unroll
    for (int d = 1; d < 64; d <<= 1) {
        int o = __shfl_up(sum, d, 64);
        if (lane >= d) sum += o;
    }
    int off   = sum - pc;           // exclusive prefix
    int total = __shfl(sum, 63, 64);
    int base  = lane << 6;
    while (m) {
        int bit = __builtin_ctzll(m);
        lds[off++] = ((base + bit) << 1) | 1;
        m &= m - 1ULL;
    }
    int padcnt = (-total) & 63;
    if (lane < padcnt) lds[total + lane] = 0;   // sentinel: idx 0, invalid
    return total;
}

// Single-type gather over a padded entry list, ascending order (bit-exact vs
// the reference's per-type sequential reduction). Sentinels contribute 0.
__device__ __forceinline__ float gather1(const int* __restrict__ lst, int npad,
                                         const float* __restrict__ base, float s) {
#pragma clang fp contract(off)
    float a = 0.0f;
    for (int k = 0; k < npad; k += 64) {
        int   e[64];
        float w[64];
#pragma unroll
        for (int u = 0; u < 64; ++u) e[u] = lst[k + u];
#pragma unroll
        for (int u = 0; u < 64; ++u) w[u] = base[(size_t)(e[u] >> 1) << 12];
#pragma unroll
        for (int u = 0; u < 64; ++u) {
            const float sc = (e[u] & 1) ? s : 0.0f;   // w*s rounding = W_eff elem
            a += w[u] * sc;
        }
    }
    return a;
}

__global__ __launch_bounds__(256) void snn_run(
    const float* __restrict__ W,       // (N,N) row j = presyn
    const float* __restrict__ Wff,     // (NI,N)
    const float* __restrict__ sf,      // (2,2)
    const float* __restrict__ sfff,    // (1,2)
    const int*   __restrict__ ci,      // (N)
    float*       __restrict__ out,     // (B,T,N)
    const unsigned long long* __restrict__ ffmask,
    const unsigned long long* __restrict__ tmask_g,
    int*         __restrict__ seq,
    unsigned long long* __restrict__ mb)
{
#pragma clang fp contract(off)
    const int tid   = threadIdx.x;
    const int lane  = tid & 63;
    const int wv    = tid >> 6;
    const int bid   = blockIdx.x;
    // hslice%8 = bid%8 pins W col-groups per XCD; b from bits {3,4,5}
    const int hslice = (((bid >> 6) & 3) << 3) | (bid & 7);   // [0,32)
    const int b      = (bid >> 3) & 7;
    const int i      = (hslice << 7) + ((wv & 1) << 6) + lane; // my post neuron
    const int g      = (hslice << 1) | (wv & 1);               // 64-post group
    const int c      = ci[i];

    const float s_exc = sf[c];
    const float s_inh = sf[2 + c];
    const float s_ff  = sfff[c];

    const unsigned long long my_tm = tmask_g[lane];

    __shared__ int   lds_e[N_NEU + 64];
    __shared__ int   lds_i[N_NEU + 64];
    __shared__ int   lds_f[N_IN + 64];
    __shared__ float fbuf[128];
    __shared__ int   s_ne, s_ni, s_nf;

    int* seqb = seq + b * 64;                             // 2-line poll row
    unsigned long long* mb_b[2] = { mb + (size_t)b * 64, mb + 512 + (size_t)b * 64 };

    // state lives in waves 2/3's registers (the epilogue owners)
    float v = -70.0f, rf = 0.0f;
    float h0 = 0.0f, h1 = 0.0f, h2 = 0.0f, h3 = 0.0f;
    float g0 = 0.0f, g1 = 0.0f, g2 = 0.0f, g3 = 0.0f;

    const float aR0 = expf(-0.1f / 0.5f);
    const float aR1 = expf(-0.1f / 2.0f);
    const float aD0 = expf(-0.1f / 2.0f);
    const float aD1 = expf(-0.1f / 100.0f);
    const float aD2 = expf(-0.1f / 5.0f);
    const float kmem   = c ? (0.1f / 10.0f) : (0.1f / 20.0f);
    const float rsteps = c ? 10.0f : 20.0f;

    for (int t = 0; t < T_STEPS; ++t) {
        // wv2: ff extraction for THIS step — poll-independent, runs in wv2's
        // own barrier slack while wv0 polls (R12 lesson: never lengthen the
        // common path; this is a different wave's idle time).
        if (wv == 2) {
            const unsigned long long mf =
                (lane < 16) ? ffmask[((size_t)b * T_STEPS + t) * 16 + lane] : 0ULL;
            const int nf = extract_f(mf, lds_f, lane);
            if (lane == 0) s_nf = nf;
        }
        if (wv == 0 && t > 0) {
            // 2-line poll (128 B), wv0 only; payload fetched once after.
            for (;;) {
                int sv = (lane < 32)
                    ? __hip_atomic_load(&seqb[lane], __ATOMIC_RELAXED,
                                        __HIP_MEMORY_SCOPE_AGENT)
                    : t;
                if (__ballot(sv >= t) == ~0ULL) break;
                __builtin_amdgcn_s_sleep(1);
            }
            asm volatile("" ::: "memory");
        }
        __syncthreads();   // A: poll passed (mask payload now safe to read)

        if (wv == 0) {
            unsigned long long mw = 0ULL;
            if (t > 0)
                mw = __hip_atomic_load(&mb_b[t & 1][lane], __ATOMIC_RELAXED,
                                       __HIP_MEMORY_SCOPE_AGENT);
            const int n = extract_f(mw & ~my_tm, lds_i, lane);   // inh list
            if (lane == 0) s_ni = n;
        } else if (wv == 1) {
            unsigned long long mw = 0ULL;
            if (t > 0)
                mw = __hip_atomic_load(&mb_b[t & 1][lane], __ATOMIC_RELAXED,
                                       __HIP_MEMORY_SCOPE_AGENT);
            const int n = extract_f(mw & my_tm, lds_e, lane);    // exc list
            if (lane == 0) s_ne = n;
        }
        __syncthreads();   // A1: lists + counts visible

        float exc = 0.0f, ffd = 0.0f, sn = 0.0f;
        bool spk = false;
        if (wv < 2) {
            // inh gather for my 64 posts; result crosses to wv+2 via LDS
            const float inh_ = gather1(lds_i, (s_ni + 63) & ~63, W + i, s_inh);
            fbuf[((wv & 1) << 6) + lane] = inh_;
        } else {
            exc = gather1(lds_e, (s_ne + 63) & ~63, W + i, s_exc);
            ffd = gather1(lds_f, (s_nf + 63) & ~63, Wff + i, s_ff);
        }
        __syncthreads();   // C: inh sums published

        if (wv >= 2) {
            const float inh = fbuf[((wv & 1) << 6) + lane];

            // ---- neuron update (identical fp op sequence to R1–R14) ----
            const float d0 = exc;
            const float d1 = 0.5f * exc;
            const float d2 = inh;
            const float d3 = ffd;

            h0 = fmaf(h0, aR0, d0);
            h1 = fmaf(h1, aR1, d1);
            h2 = fmaf(h2, aR0, d2);
            h3 = fmaf(h3, aR0, d3);
            g0 = fmaf(g0, aD0, (1.0f - aD0) * h0);
            g1 = fmaf(g1, aD1, (1.0f - aD1) * h1);
            g2 = fmaf(g2, aD2, (1.0f - aD2) * h2);
            g3 = fmaf(g3, aD0, (1.0f - aD0) * h3);

            const float p0 = g0 * (0.0f - v);
            const float p1 = g1 * (0.0f - v);
            const float p2 = g2 * (-80.0f - v);
            const float p3 = g3 * (0.0f - v);
            const float Isyn = ((p0 + p1) + p2) + p3;

            float vn = fmaf(kmem, (-70.0f - v) + Isyn / 10.0f, v);
            const bool refr = rf > 0.0f;
            if (refr) vn = -65.0f;
            sn  = (!refr && (vn > -50.0f)) ? 1.0f : 0.0f;
            spk = sn > 0.5f;
            v  = spk ? -65.0f : vn;
            rf = spk ? rsteps : fmaxf(rf - 1.0f, 0.0f);

            // publish my group's spike word for step t+1
            const unsigned long long sm = __ballot(spk);
            if (lane == 0)
                __hip_atomic_store(&mb_b[(t + 1) & 1][g], sm,
                                   __ATOMIC_RELAXED, __HIP_MEMORY_SCOPE_AGENT);
        }
        __builtin_amdgcn_s_waitcnt(0);   // wv2/3: drain mask word to IF
        __syncthreads();                 // B: both mask words drained
        if (wv == 0 && lane == 0)
            __hip_atomic_store(&seqb[hslice], t + 1,
                               __ATOMIC_RELAXED, __HIP_MEMORY_SCOPE_AGENT);
        if (wv >= 2)
            out[((size_t)b * T_STEPS + t) * N_NEU + i] = sn;   // fire-and-forget
        // lds rewrite safety: wv2's ff extract for t+1 follows its own gather
        // (same wave); lds_e/lds_i rewrites happen after the t+1 poll, which
        // requires this block's seq (post-B) — B follows every lds read of t.
    }
}

extern "C" void kernel_launch(void* const* d_in, const int* in_sizes, int n_in,
                              void* d_out, int out_size, void* d_ws, size_t ws_size,
                              hipStream_t stream) {
    const float* inspk = (const float*)d_in[0];
    const float* W     = (const float*)d_in[1];
    const float* Wff   = (const float*)d_in[2];
    const float* sf    = (const float*)d_in[3];
    const float* sfff  = (const float*)d_in[4];
    const int*   ci    = (const int*)d_in[5];

    float* out = (float*)d_out;
    int*                seq    = (int*)((char*)d_ws + WS_SEQ_OFF);
    unsigned long long* tmask  = (unsigned long long*)((char*)d_ws + WS_TM_OFF);
    unsigned long long* mb     = (unsigned long long*)((char*)d_ws + WS_MB_OFF);
    unsigned long long* ffmask = (unsigned long long*)((char*)d_ws + WS_FFM_OFF);

    snn_init<<<64, 64, 0, stream>>>(ci, seq, tmask, mb);
    snn_ffmask<<<1000, 256, 0, stream>>>(inspk, ffmask);
    snn_run<<<NBLK, 256, 0, stream>>>(W, Wff, sf, sfff, ci, out,
                                      ffmask, tmask, seq, mb);
}